// Round 1
// baseline (61823.083 us; speedup 1.0000x reference)
//
#include <hip/hip_runtime.h>

// Problem constants (shapes fixed by setup_inputs()).
#define B_ 1024
#define D_ 1024
#define F_ 32768
#define T_ 32
#define KSLOTS 32

// ---------- packed argmax key: (sortable float << 32) | (0xFFFFFFFF - idx) ----------
// Monotone in value; for equal values, larger key <=> smaller idx (matches jnp.argmax
// first-occurrence tie-break).
__device__ __forceinline__ unsigned int fkey(float f) {
    unsigned int u = __float_as_uint(f);
    return (u & 0x80000000u) ? ~u : (u | 0x80000000u);
}
__device__ __forceinline__ unsigned long long packkey(float v, unsigned int n) {
    return ((unsigned long long)fkey(v) << 32) | (unsigned long long)(0xFFFFFFFFu - n);
}

// ---------------------------- init: r = x, cnt = 0, amax = 0 ----------------------------
__global__ __launch_bounds__(256) void init_kernel(
    const float* __restrict__ X, float* __restrict__ Rres,
    int* __restrict__ a_cnt, unsigned long long* __restrict__ amax)
{
    const int b = blockIdx.x, tid = threadIdx.x;
    for (int d = tid; d < D_; d += 256) Rres[(size_t)b * D_ + d] = X[(size_t)b * D_ + d];
    if (tid == 0) { a_cnt[b] = 0; amax[b] = 0ull; }
}

// ------------------- fused SGEMM (ip = r @ xs^T) + per-row argmax -------------------
// A = Rres [B_,D_] row-major, B = XS [F_,D_] row-major (both K-contiguous).
// Tile 128x128, BK=16, 256 threads, 8x8 micro-tile per thread.
// Accumulation is a single strictly-ascending-k fmaf chain per output (matches BLAS
// microkernel rounding as closely as possible -> minimizes argmax flips vs np ref).
__global__ __launch_bounds__(256, 4) void gemm_argmax_kernel(
    const float* __restrict__ R, const float* __restrict__ XS,
    unsigned long long* __restrict__ amax)
{
    __shared__ float As[16][132];   // [k][m], +4 pad keeps 16B alignment, <=2-way conflicts
    __shared__ float Bs[16][132];   // [k][n]
    __shared__ unsigned long long red[128][16];

    const int tid = threadIdx.x;
    const int bn = blockIdx.x;          // 0..255  (N tiles)
    const int bm = blockIdx.y;          // 0..7    (M tiles)
    const int m0 = bm * 128;
    const int n0 = bn * 128;

    const int lrow = tid >> 2;          // 0..63
    const int lq   = tid & 3;           // float4 slot within 16 floats of k
    const float* Aptr = R  + (size_t)(m0 + lrow) * D_ + lq * 4;
    const float* Bptr = XS + (size_t)(n0 + lrow) * D_ + lq * 4;

    const int tx = tid & 15;            // n sub-tile
    const int ty = tid >> 4;            // m sub-tile

    float acc[8][8];
#pragma unroll
    for (int i = 0; i < 8; ++i)
#pragma unroll
        for (int j = 0; j < 8; ++j) acc[i][j] = 0.f;

    // prefetch first tiles
    float4 a0 = *(const float4*)(Aptr);
    float4 a1 = *(const float4*)(Aptr + (size_t)64 * D_);
    float4 b0 = *(const float4*)(Bptr);
    float4 b1 = *(const float4*)(Bptr + (size_t)64 * D_);

    for (int k0 = 0; k0 < D_; k0 += 16) {
        __syncthreads();   // previous compute done before overwriting LDS
        As[lq*4+0][lrow] = a0.x; As[lq*4+1][lrow] = a0.y;
        As[lq*4+2][lrow] = a0.z; As[lq*4+3][lrow] = a0.w;
        As[lq*4+0][64+lrow] = a1.x; As[lq*4+1][64+lrow] = a1.y;
        As[lq*4+2][64+lrow] = a1.z; As[lq*4+3][64+lrow] = a1.w;
        Bs[lq*4+0][lrow] = b0.x; Bs[lq*4+1][lrow] = b0.y;
        Bs[lq*4+2][lrow] = b0.z; Bs[lq*4+3][lrow] = b0.w;
        Bs[lq*4+0][64+lrow] = b1.x; Bs[lq*4+1][64+lrow] = b1.y;
        Bs[lq*4+2][64+lrow] = b1.z; Bs[lq*4+3][64+lrow] = b1.w;
        __syncthreads();
        if (k0 + 16 < D_) {   // prefetch next tile while computing this one
            a0 = *(const float4*)(Aptr + k0 + 16);
            a1 = *(const float4*)(Aptr + (size_t)64 * D_ + k0 + 16);
            b0 = *(const float4*)(Bptr + k0 + 16);
            b1 = *(const float4*)(Bptr + (size_t)64 * D_ + k0 + 16);
        }
#pragma unroll
        for (int kk = 0; kk < 16; ++kk) {
            float4 av0 = *(const float4*)(&As[kk][ty*4]);
            float4 av1 = *(const float4*)(&As[kk][64+ty*4]);
            float4 bv0 = *(const float4*)(&Bs[kk][tx*4]);
            float4 bv1 = *(const float4*)(&Bs[kk][64+tx*4]);
            float a[8] = {av0.x, av0.y, av0.z, av0.w, av1.x, av1.y, av1.z, av1.w};
            float bb[8] = {bv0.x, bv0.y, bv0.z, bv0.w, bv1.x, bv1.y, bv1.z, bv1.w};
#pragma unroll
            for (int i = 0; i < 8; ++i)
#pragma unroll
                for (int j = 0; j < 8; ++j)
                    acc[i][j] = fmaf(a[i], bb[j], acc[i][j]);
        }
    }

    // ---- argmax epilogue: per-thread best per m-row, then cross-thread via LDS ----
#pragma unroll
    for (int i = 0; i < 8; ++i) {
        const int mloc = (i < 4) ? (ty*4 + i) : (64 + ty*4 + (i - 4));
        unsigned long long best = 0ull;
#pragma unroll
        for (int j = 0; j < 8; ++j) {
            const int nloc = (j < 4) ? (tx*4 + j) : (64 + tx*4 + (j - 4));
            unsigned long long key = packkey(acc[i][j], (unsigned int)(n0 + nloc));
            best = (key > best) ? key : best;
        }
        red[mloc][tx] = best;
    }
    __syncthreads();
    if (tid < 128) {
        unsigned long long best = red[tid][0];
#pragma unroll
        for (int c = 1; c < 16; ++c) {
            unsigned long long k = red[tid][c];
            best = (k > best) ? k : best;
        }
        atomicMax(&amax[m0 + tid], best);
    }
}

// ----------------- per-row sparse update: select, grad, step, relu, residual -----------------
__global__ __launch_bounds__(256) void update_kernel(
    const float* __restrict__ X, const float* __restrict__ XS,
    float* __restrict__ Rres,
    int* __restrict__ a_idx, float* __restrict__ a_w, int* __restrict__ a_cnt,
    unsigned long long* __restrict__ amax)
{
    const int b = blockIdx.x;
    const int tid = threadIdx.x;
    __shared__ float s_r[D_];
    __shared__ int   s_idx[33];
    __shared__ float s_w[33];
    __shared__ float s_g[33];
    __shared__ int   s_cnt;
    __shared__ float s_red[8];

    for (int d = tid; d < D_; d += 256) s_r[d] = Rres[(size_t)b * D_ + d];

    if (tid == 0) {
        int cnt = a_cnt[b];
        for (int j = 0; j < cnt; ++j) { s_idx[j] = a_idx[b*KSLOTS + j]; s_w[j] = a_w[b*KSLOTS + j]; }
        unsigned long long key = amax[b];
        int ni = (int)(0xFFFFFFFFu - (unsigned int)(key & 0xFFFFFFFFull));
        bool found = false;
        for (int j = 0; j < cnt; ++j) found = found || (s_idx[j] == ni);
        if (!found) {  // insert keeping indices ascending (matches numpy's sum-over-f order)
            int p = cnt;
            while (p > 0 && s_idx[p-1] > ni) { s_idx[p] = s_idx[p-1]; s_w[p] = s_w[p-1]; --p; }
            s_idx[p] = ni; s_w[p] = 0.f; ++cnt;
        }
        s_cnt = cnt;
    }
    __syncthreads();
    const int cnt = s_cnt;
    const int wave = tid >> 6, lane = tid & 63;

    // grad_j = <r, xs[idx_j]> for each selected atom (one wave per atom, round-robin)
    for (int j = wave; j < cnt; j += 4) {
        const float* xr = XS + (size_t)s_idx[j] * D_;
        float sum = 0.f;
#pragma unroll
        for (int i = 0; i < D_/64; ++i) { int d = lane + (i << 6); sum = fmaf(s_r[d], xr[d], sum); }
        for (int off = 32; off > 0; off >>= 1) sum += __shfl_down(sum, off);
        if (lane == 0) s_g[j] = sum;
    }
    __syncthreads();

    // c = grad @ xs (only over active atoms, ascending index); reduce c.c and c.r
    float cs = 0.f, cr = 0.f;
#pragma unroll
    for (int v = 0; v < 4; ++v) {
        const int d = tid + (v << 8);
        float cv = 0.f;
        for (int j = 0; j < cnt; ++j) cv = fmaf(s_g[j], XS[(size_t)s_idx[j]*D_ + d], cv);
        cs = fmaf(cv, cv, cs);
        cr = fmaf(cv, s_r[d], cr);
    }
    for (int off = 32; off > 0; off >>= 1) { cs += __shfl_down(cs, off); cr += __shfl_down(cr, off); }
    if (lane == 0) { s_red[wave] = cs; s_red[4 + wave] = cr; }
    __syncthreads();

    if (tid == 0) {
        const float cs_t = s_red[0] + s_red[1] + s_red[2] + s_red[3];
        const float cr_t = s_red[4] + s_red[5] + s_red[6] + s_red[7];
        const float ss = cr_t / fmaxf(cs_t, 1e-3f);
        int nc = 0;
        for (int j = 0; j < cnt; ++j) {           // weights = relu(w + ss*grad), drop zeros
            float nw = s_w[j] + ss * s_g[j];
            if (nw > 0.f) { s_idx[nc] = s_idx[j]; s_w[nc] = nw; ++nc; }
        }
        s_cnt = nc;
        a_cnt[b] = nc;
        for (int j = 0; j < nc; ++j) { a_idx[b*KSLOTS + j] = s_idx[j]; a_w[b*KSLOTS + j] = s_w[j]; }
        amax[b] = 0ull;                            // reset for next step's GEMM
    }
    __syncthreads();
    const int nc = s_cnt;

    // fresh residual: r = x - sum_j w_j * xs[idx_j]  (ascending index, sum-then-subtract)
#pragma unroll
    for (int v = 0; v < 4; ++v) {
        const int d = tid + (v << 8);
        float s = 0.f;
        for (int j = 0; j < nc; ++j) s = fmaf(s_w[j], XS[(size_t)s_idx[j]*D_ + d], s);
        Rres[(size_t)b*D_ + d] = X[(size_t)b*D_ + d] - s;
    }
}

// ----------------- finalize: top_k, decode x/y, losses, write outputs -----------------
__global__ __launch_bounds__(256) void finalize_kernel(
    const float* __restrict__ Y,
    const float* __restrict__ XS, const float* __restrict__ YS,
    const int* __restrict__ a_idx, const float* __restrict__ a_w, const int* __restrict__ a_cnt,
    float* __restrict__ out)
{
    const int b = blockIdx.x, tid = threadIdx.x;
    __shared__ int   s_idx[KSLOTS];
    __shared__ float s_w[KSLOTS];
    __shared__ int   o_idx[KSLOTS];
    __shared__ float o_w[KSLOTS];
    __shared__ float s_red[4];

    if (tid == 0) {
        int cnt = a_cnt[b];
        for (int j = 0; j < cnt; ++j) { s_idx[j] = a_idx[b*KSLOTS + j]; s_w[j] = a_w[b*KSLOTS + j]; }
        // insertion sort: desc weight, ties -> ascending index (lax.top_k semantics)
        for (int i = 1; i < cnt; ++i) {
            int ii = s_idx[i]; float ww = s_w[i];
            int p = i - 1;
            while (p >= 0 && (s_w[p] < ww || (s_w[p] == ww && s_idx[p] > ii))) {
                s_w[p+1] = s_w[p]; s_idx[p+1] = s_idx[p]; --p;
            }
            s_w[p+1] = ww; s_idx[p+1] = ii;
        }
        for (int j = 0; j < cnt; ++j) { o_idx[j] = s_idx[j]; o_w[j] = s_w[j]; }
        // pad remaining slots with the smallest indices whose weight is zero
        int p = cnt, f = 0;
        while (p < KSLOTS) {
            bool member = false;
            for (int j = 0; j < cnt; ++j) member = member || (s_idx[j] == f);
            if (!member) { o_idx[p] = f; o_w[p] = 0.f; ++p; }
            ++f;
        }
    }
    __syncthreads();

    if (tid < KSLOTS) {
        out[(size_t)b*KSLOTS + tid] = o_w[tid];
        out[32768 + (size_t)b*KSLOTS + tid] = (float)o_idx[tid];   // harness reads fp32
    }

    float lsum = 0.f;
    for (int d = tid; d < D_; d += 256) {
        float xr = 0.f, yr = 0.f;
#pragma unroll
        for (int k = 0; k < KSLOTS; ++k) {
            const size_t off = (size_t)o_idx[k] * D_ + d;
            xr = fmaf(o_w[k], XS[off], xr);
            yr = fmaf(o_w[k], YS[off], yr);
        }
        out[65536 + (size_t)b*D_ + d] = xr;
        out[65536 + 1048576 + (size_t)b*D_ + d] = yr;
        const float e = yr - Y[(size_t)b*D_ + d];
        lsum = fmaf(e, e, lsum);
    }
    const int wave = tid >> 6, lane = tid & 63;
    for (int off = 32; off > 0; off >>= 1) lsum += __shfl_down(lsum, off);
    if (lane == 0) s_red[wave] = lsum;
    __syncthreads();
    if (tid == 0) out[65536 + 2097152 + b] = s_red[0] + s_red[1] + s_red[2] + s_red[3];
}

extern "C" void kernel_launch(void* const* d_in, const int* in_sizes, int n_in,
                              void* d_out, int out_size, void* d_ws, size_t ws_size,
                              hipStream_t stream) {
    (void)in_sizes; (void)n_in; (void)out_size; (void)ws_size;
    const float* x  = (const float*)d_in[0];
    const float* y  = (const float*)d_in[1];
    const float* xs = (const float*)d_in[2];
    const float* ys = (const float*)d_in[3];
    // d_in[4] = target_l0 (hardcoded 32; shapes are fixed)
    float* out = (float*)d_out;

    // workspace layout (~4.3 MB)
    char* ws = (char*)d_ws;
    float*              Rres  = (float*)(ws);                                   // 4 MB
    unsigned long long* amax  = (unsigned long long*)(ws + 4*1024*1024);        // 8 KB
    int*                a_cnt = (int*)(ws + 4*1024*1024 + 8192);                // 4 KB
    int*                a_idx = (int*)(ws + 4*1024*1024 + 8192 + 4096);         // 128 KB
    float*              a_w   = (float*)(ws + 4*1024*1024 + 8192 + 4096 + 131072); // 128 KB

    init_kernel<<<B_, 256, 0, stream>>>(x, Rres, a_cnt, amax);

    dim3 ggrid(F_/128, B_/128);   // (256, 8)
    for (int t = 0; t < T_; ++t) {
        gemm_argmax_kernel<<<ggrid, 256, 0, stream>>>(Rres, xs, amax);
        update_kernel<<<B_, 256, 0, stream>>>(x, xs, Rres, a_idx, a_w, a_cnt, amax);
    }
    finalize_kernel<<<B_, 256, 0, stream>>>(y, xs, ys, a_idx, a_w, a_cnt, out);
}

// Round 2
// 26201.157 us; speedup vs baseline: 2.3596x; 2.3596x over previous
//
#include <hip/hip_runtime.h>

// Problem constants (shapes fixed by setup_inputs()).
#define B_ 1024
#define D_ 1024
#define F_ 32768
#define T_ 32
#define KSLOTS 32

// ---------- packed argmax key: (sortable float << 32) | (0xFFFFFFFF - idx) ----------
// Monotone in value; for equal values, larger key <=> smaller idx (matches jnp.argmax
// first-occurrence tie-break).
__device__ __forceinline__ unsigned int fkey(float f) {
    unsigned int u = __float_as_uint(f);
    return (u & 0x80000000u) ? ~u : (u | 0x80000000u);
}
__device__ __forceinline__ unsigned long long packkey(float v, unsigned int n) {
    return ((unsigned long long)fkey(v) << 32) | (unsigned long long)(0xFFFFFFFFu - n);
}

// ---------------------------- init: r = x, cnt = 0, amax = 0 ----------------------------
__global__ __launch_bounds__(256) void init_kernel(
    const float* __restrict__ X, float* __restrict__ Rres,
    int* __restrict__ a_cnt, unsigned long long* __restrict__ amax)
{
    const int b = blockIdx.x, tid = threadIdx.x;
    for (int d = tid; d < D_; d += 256) Rres[(size_t)b * D_ + d] = X[(size_t)b * D_ + d];
    if (tid == 0) { a_cnt[b] = 0; amax[b] = 0ull; }
}

// ------------------- fused SGEMM (ip = r @ xs^T) + per-row argmax -------------------
// A = Rres [B_,D_] row-major, B = XS [F_,D_] row-major (both K-contiguous).
// Tile 128x128, BK=16, 256 threads, 8x8 micro-tile per thread.
// __launch_bounds__(256,2): 256-VGPR cap. (256,4) made the allocator pin 64 VGPRs and
// spill the 64-float accumulator to scratch -> 6 GB/dispatch scratch writes (R1 rocprof).
__global__ __launch_bounds__(256, 2) void gemm_argmax_kernel(
    const float* __restrict__ R, const float* __restrict__ XS,
    unsigned long long* __restrict__ amax)
{
    __shared__ float As[16][132];   // [k][m], +4 pad keeps 16B alignment, <=2-way conflicts
    __shared__ float Bs[16][132];   // [k][n]
    __shared__ unsigned long long red[128][16];

    const int tid = threadIdx.x;
    const int bm = blockIdx.x;          // 0..7    (M tiles) — x-fastest so the 8 blocks
    const int bn = blockIdx.y;          // 0..255  (N tiles)   sharing one XS slab co-run
    const int m0 = bm * 128;
    const int n0 = bn * 128;

    const int lrow = tid >> 2;          // 0..63
    const int lq   = tid & 3;           // float4 slot within 16 floats of k
    const float* Aptr = R  + (size_t)(m0 + lrow) * D_ + lq * 4;
    const float* Bptr = XS + (size_t)(n0 + lrow) * D_ + lq * 4;

    const int tx = tid & 15;            // n sub-tile
    const int ty = tid >> 4;            // m sub-tile

    float acc[8][8];
#pragma unroll
    for (int i = 0; i < 8; ++i)
#pragma unroll
        for (int j = 0; j < 8; ++j) acc[i][j] = 0.f;

    // prefetch first tiles
    float4 a0 = *(const float4*)(Aptr);
    float4 a1 = *(const float4*)(Aptr + (size_t)64 * D_);
    float4 b0 = *(const float4*)(Bptr);
    float4 b1 = *(const float4*)(Bptr + (size_t)64 * D_);

    for (int k0 = 0; k0 < D_; k0 += 16) {
        __syncthreads();   // previous compute done before overwriting LDS
        As[lq*4+0][lrow] = a0.x; As[lq*4+1][lrow] = a0.y;
        As[lq*4+2][lrow] = a0.z; As[lq*4+3][lrow] = a0.w;
        As[lq*4+0][64+lrow] = a1.x; As[lq*4+1][64+lrow] = a1.y;
        As[lq*4+2][64+lrow] = a1.z; As[lq*4+3][64+lrow] = a1.w;
        Bs[lq*4+0][lrow] = b0.x; Bs[lq*4+1][lrow] = b0.y;
        Bs[lq*4+2][lrow] = b0.z; Bs[lq*4+3][lrow] = b0.w;
        Bs[lq*4+0][64+lrow] = b1.x; Bs[lq*4+1][64+lrow] = b1.y;
        Bs[lq*4+2][64+lrow] = b1.z; Bs[lq*4+3][64+lrow] = b1.w;
        __syncthreads();
        if (k0 + 16 < D_) {   // prefetch next tile while computing this one
            a0 = *(const float4*)(Aptr + k0 + 16);
            a1 = *(const float4*)(Aptr + (size_t)64 * D_ + k0 + 16);
            b0 = *(const float4*)(Bptr + k0 + 16);
            b1 = *(const float4*)(Bptr + (size_t)64 * D_ + k0 + 16);
        }
#pragma unroll
        for (int kk = 0; kk < 16; ++kk) {
            float4 av0 = *(const float4*)(&As[kk][ty*4]);
            float4 av1 = *(const float4*)(&As[kk][64+ty*4]);
            float4 bv0 = *(const float4*)(&Bs[kk][tx*4]);
            float4 bv1 = *(const float4*)(&Bs[kk][64+tx*4]);
            float a[8] = {av0.x, av0.y, av0.z, av0.w, av1.x, av1.y, av1.z, av1.w};
            float bb[8] = {bv0.x, bv0.y, bv0.z, bv0.w, bv1.x, bv1.y, bv1.z, bv1.w};
#pragma unroll
            for (int i = 0; i < 8; ++i)
#pragma unroll
                for (int j = 0; j < 8; ++j)
                    acc[i][j] = fmaf(a[i], bb[j], acc[i][j]);
        }
    }

    // ---- argmax epilogue: per-thread best per m-row, then cross-thread via LDS ----
#pragma unroll
    for (int i = 0; i < 8; ++i) {
        const int mloc = (i < 4) ? (ty*4 + i) : (64 + ty*4 + (i - 4));
        unsigned long long best = 0ull;
#pragma unroll
        for (int j = 0; j < 8; ++j) {
            const int nloc = (j < 4) ? (tx*4 + j) : (64 + tx*4 + (j - 4));
            unsigned long long key = packkey(acc[i][j], (unsigned int)(n0 + nloc));
            best = (key > best) ? key : best;
        }
        red[mloc][tx] = best;
    }
    __syncthreads();
    if (tid < 128) {
        unsigned long long best = red[tid][0];
#pragma unroll
        for (int c = 1; c < 16; ++c) {
            unsigned long long k = red[tid][c];
            best = (k > best) ? k : best;
        }
        atomicMax(&amax[m0 + tid], best);
    }
}

// ----------------- per-row sparse update: select, grad, step, relu, residual -----------------
__global__ __launch_bounds__(256) void update_kernel(
    const float* __restrict__ X, const float* __restrict__ XS,
    float* __restrict__ Rres,
    int* __restrict__ a_idx, float* __restrict__ a_w, int* __restrict__ a_cnt,
    unsigned long long* __restrict__ amax)
{
    const int b = blockIdx.x;
    const int tid = threadIdx.x;
    __shared__ float s_r[D_];
    __shared__ int   s_idx[33];
    __shared__ float s_w[33];
    __shared__ float s_g[33];
    __shared__ int   s_cnt;
    __shared__ float s_red[8];

    for (int d = tid; d < D_; d += 256) s_r[d] = Rres[(size_t)b * D_ + d];

    if (tid == 0) {
        int cnt = a_cnt[b];
        for (int j = 0; j < cnt; ++j) { s_idx[j] = a_idx[b*KSLOTS + j]; s_w[j] = a_w[b*KSLOTS + j]; }
        unsigned long long key = amax[b];
        int ni = (int)(0xFFFFFFFFu - (unsigned int)(key & 0xFFFFFFFFull));
        bool found = false;
        for (int j = 0; j < cnt; ++j) found = found || (s_idx[j] == ni);
        if (!found) {  // insert keeping indices ascending (matches numpy's sum-over-f order)
            int p = cnt;
            while (p > 0 && s_idx[p-1] > ni) { s_idx[p] = s_idx[p-1]; s_w[p] = s_w[p-1]; --p; }
            s_idx[p] = ni; s_w[p] = 0.f; ++cnt;
        }
        s_cnt = cnt;
    }
    __syncthreads();
    const int cnt = s_cnt;
    const int wave = tid >> 6, lane = tid & 63;

    // grad_j = <r, xs[idx_j]> for each selected atom (one wave per atom, round-robin)
    for (int j = wave; j < cnt; j += 4) {
        const float* xr = XS + (size_t)s_idx[j] * D_;
        float sum = 0.f;
#pragma unroll
        for (int i = 0; i < D_/64; ++i) { int d = lane + (i << 6); sum = fmaf(s_r[d], xr[d], sum); }
        for (int off = 32; off > 0; off >>= 1) sum += __shfl_down(sum, off);
        if (lane == 0) s_g[j] = sum;
    }
    __syncthreads();

    // c = grad @ xs (only over active atoms, ascending index); reduce c.c and c.r
    float cs = 0.f, cr = 0.f;
#pragma unroll
    for (int v = 0; v < 4; ++v) {
        const int d = tid + (v << 8);
        float cv = 0.f;
        for (int j = 0; j < cnt; ++j) cv = fmaf(s_g[j], XS[(size_t)s_idx[j]*D_ + d], cv);
        cs = fmaf(cv, cv, cs);
        cr = fmaf(cv, s_r[d], cr);
    }
    for (int off = 32; off > 0; off >>= 1) { cs += __shfl_down(cs, off); cr += __shfl_down(cr, off); }
    if (lane == 0) { s_red[wave] = cs; s_red[4 + wave] = cr; }
    __syncthreads();

    if (tid == 0) {
        const float cs_t = s_red[0] + s_red[1] + s_red[2] + s_red[3];
        const float cr_t = s_red[4] + s_red[5] + s_red[6] + s_red[7];
        const float ss = cr_t / fmaxf(cs_t, 1e-3f);
        int nc = 0;
        for (int j = 0; j < cnt; ++j) {           // weights = relu(w + ss*grad), drop zeros
            float nw = s_w[j] + ss * s_g[j];
            if (nw > 0.f) { s_idx[nc] = s_idx[j]; s_w[nc] = nw; ++nc; }
        }
        s_cnt = nc;
        a_cnt[b] = nc;
        for (int j = 0; j < nc; ++j) { a_idx[b*KSLOTS + j] = s_idx[j]; a_w[b*KSLOTS + j] = s_w[j]; }
        amax[b] = 0ull;                            // reset for next step's GEMM
    }
    __syncthreads();
    const int nc = s_cnt;

    // fresh residual: r = x - sum_j w_j * xs[idx_j]  (ascending index, sum-then-subtract)
#pragma unroll
    for (int v = 0; v < 4; ++v) {
        const int d = tid + (v << 8);
        float s = 0.f;
        for (int j = 0; j < nc; ++j) s = fmaf(s_w[j], XS[(size_t)s_idx[j]*D_ + d], s);
        Rres[(size_t)b*D_ + d] = X[(size_t)b*D_ + d] - s;
    }
}

// ----------------- finalize: top_k, decode x/y, losses, write outputs -----------------
__global__ __launch_bounds__(256) void finalize_kernel(
    const float* __restrict__ Y,
    const float* __restrict__ XS, const float* __restrict__ YS,
    const int* __restrict__ a_idx, const float* __restrict__ a_w, const int* __restrict__ a_cnt,
    float* __restrict__ out)
{
    const int b = blockIdx.x, tid = threadIdx.x;
    __shared__ int   s_idx[KSLOTS];
    __shared__ float s_w[KSLOTS];
    __shared__ int   o_idx[KSLOTS];
    __shared__ float o_w[KSLOTS];
    __shared__ float s_red[4];

    if (tid == 0) {
        int cnt = a_cnt[b];
        for (int j = 0; j < cnt; ++j) { s_idx[j] = a_idx[b*KSLOTS + j]; s_w[j] = a_w[b*KSLOTS + j]; }
        // insertion sort: desc weight, ties -> ascending index (lax.top_k semantics)
        for (int i = 1; i < cnt; ++i) {
            int ii = s_idx[i]; float ww = s_w[i];
            int p = i - 1;
            while (p >= 0 && (s_w[p] < ww || (s_w[p] == ww && s_idx[p] > ii))) {
                s_w[p+1] = s_w[p]; s_idx[p+1] = s_idx[p]; --p;
            }
            s_w[p+1] = ww; s_idx[p+1] = ii;
        }
        for (int j = 0; j < cnt; ++j) { o_idx[j] = s_idx[j]; o_w[j] = s_w[j]; }
        // pad remaining slots with the smallest indices whose weight is zero
        int p = cnt, f = 0;
        while (p < KSLOTS) {
            bool member = false;
            for (int j = 0; j < cnt; ++j) member = member || (s_idx[j] == f);
            if (!member) { o_idx[p] = f; o_w[p] = 0.f; ++p; }
            ++f;
        }
    }
    __syncthreads();

    if (tid < KSLOTS) {
        out[(size_t)b*KSLOTS + tid] = o_w[tid];
        out[32768 + (size_t)b*KSLOTS + tid] = (float)o_idx[tid];   // harness reads fp32
    }

    float lsum = 0.f;
    for (int d = tid; d < D_; d += 256) {
        float xr = 0.f, yr = 0.f;
#pragma unroll
        for (int k = 0; k < KSLOTS; ++k) {
            const size_t off = (size_t)o_idx[k] * D_ + d;
            xr = fmaf(o_w[k], XS[off], xr);
            yr = fmaf(o_w[k], YS[off], yr);
        }
        out[65536 + (size_t)b*D_ + d] = xr;
        out[65536 + 1048576 + (size_t)b*D_ + d] = yr;
        const float e = yr - Y[(size_t)b*D_ + d];
        lsum = fmaf(e, e, lsum);
    }
    const int wave = tid >> 6, lane = tid & 63;
    for (int off = 32; off > 0; off >>= 1) lsum += __shfl_down(lsum, off);
    if (lane == 0) s_red[wave] = lsum;
    __syncthreads();
    if (tid == 0) out[65536 + 2097152 + b] = s_red[0] + s_red[1] + s_red[2] + s_red[3];
}

extern "C" void kernel_launch(void* const* d_in, const int* in_sizes, int n_in,
                              void* d_out, int out_size, void* d_ws, size_t ws_size,
                              hipStream_t stream) {
    (void)in_sizes; (void)n_in; (void)out_size; (void)ws_size;
    const float* x  = (const float*)d_in[0];
    const float* y  = (const float*)d_in[1];
    const float* xs = (const float*)d_in[2];
    const float* ys = (const float*)d_in[3];
    // d_in[4] = target_l0 (hardcoded 32; shapes are fixed)
    float* out = (float*)d_out;

    // workspace layout (~4.3 MB)
    char* ws = (char*)d_ws;
    float*              Rres  = (float*)(ws);                                   // 4 MB
    unsigned long long* amax  = (unsigned long long*)(ws + 4*1024*1024);        // 8 KB
    int*                a_cnt = (int*)(ws + 4*1024*1024 + 8192);                // 4 KB
    int*                a_idx = (int*)(ws + 4*1024*1024 + 8192 + 4096);         // 128 KB
    float*              a_w   = (float*)(ws + 4*1024*1024 + 8192 + 4096 + 131072); // 128 KB

    init_kernel<<<B_, 256, 0, stream>>>(x, Rres, a_cnt, amax);

    dim3 ggrid(B_/128, F_/128);   // (8, 256): bm fastest -> XS-slab sharers co-resident
    for (int t = 0; t < T_; ++t) {
        gemm_argmax_kernel<<<ggrid, 256, 0, stream>>>(Rres, xs, amax);
        update_kernel<<<B_, 256, 0, stream>>>(x, xs, Rres, a_idx, a_w, a_cnt, amax);
    }
    finalize_kernel<<<B_, 256, 0, stream>>>(y, xs, ys, a_idx, a_w, a_cnt, out);
}